// Round 1
// baseline (469.981 us; speedup 1.0000x reference)
//
#include <hip/hip_runtime.h>

// ---------------------------------------------------------------------------
// SlidingWindowGroupedAttention  (B=2, L=8192, E=1024, H=16, D=64, W=512, G=64)
// Pipeline: cvt(f32->bf16) -> GEMM+RoPE (Q,K) -> GEMM->vT (V, first 512 rows)
//           -> grouped attention -> GEMM (+bias, fp32 out)
// ---------------------------------------------------------------------------

typedef unsigned short ushort_t;
typedef __attribute__((ext_vector_type(8))) __bf16 bf16x8;
typedef __attribute__((ext_vector_type(4))) float f32x4;
typedef __attribute__((ext_vector_type(8))) unsigned short ushort8;

#define MFMA16(a, b, c) __builtin_amdgcn_mfma_f32_16x16x32_bf16((a), (b), (c), 0, 0, 0)

static __device__ __forceinline__ ushort_t f2bf(float f) {
    unsigned u = __float_as_uint(f);
    u += 0x7fffu + ((u >> 16) & 1u);   // round-to-nearest-even
    return (ushort_t)(u >> 16);
}

typedef __attribute__((address_space(3))) unsigned int lds_u32;
typedef const __attribute__((address_space(1))) unsigned int glb_u32;

static __device__ __forceinline__ void gload_lds16(const void* g, void* l) {
    __builtin_amdgcn_global_load_lds((glb_u32*)g, (lds_u32*)l, 16, 0, 0);
}

// ---------------------------------------------------------------------------
// fp32 -> bf16 convert, 8 elems/thread
// ---------------------------------------------------------------------------
__global__ __launch_bounds__(256) void cvt_bf16(const float* __restrict__ in,
                                                ushort_t* __restrict__ out, long n8) {
    long i = (long)blockIdx.x * 256 + threadIdx.x;
    if (i >= n8) return;
    const float4* p = (const float4*)in + i * 2;
    float4 a = p[0], b = p[1];
    ushort8 o;
    o[0] = f2bf(a.x); o[1] = f2bf(a.y); o[2] = f2bf(a.z); o[3] = f2bf(a.w);
    o[4] = f2bf(b.x); o[5] = f2bf(b.y); o[6] = f2bf(b.z); o[7] = f2bf(b.w);
    *(ushort8*)(out + i * 8) = o;
}

// value: compact rows (b, l<512) -> (b*512+l) and convert
__global__ __launch_bounds__(256) void cvt_value(const float* __restrict__ in,
                                                 ushort_t* __restrict__ out) {
    int i = blockIdx.x * 256 + threadIdx.x;  // 131072 threads, 8 elems each
    int f = i * 8;
    int m = f >> 10, c = f & 1023;
    long src = ((long)(m >> 9) * 8192 + (m & 511)) * 1024 + c;
    const float4* p = (const float4*)(in + src);
    float4 a = p[0], b = p[1];
    ushort8 o;
    o[0] = f2bf(a.x); o[1] = f2bf(a.y); o[2] = f2bf(a.z); o[3] = f2bf(a.w);
    o[4] = f2bf(b.x); o[5] = f2bf(b.y); o[6] = f2bf(b.z); o[7] = f2bf(b.w);
    *(ushort8*)(out + f) = o;
}

// sin/cos table: tab[pos*32 + j] = (sin(pos*invf_j), cos(pos*invf_j))
__global__ __launch_bounds__(256) void rope_tab(float2* __restrict__ tab) {
    int i = blockIdx.x * 256 + threadIdx.x;  // 8192*32
    int l = i >> 5, j = i & 31;
    float inv = exp2f(-(float)j * 0.4152410118609203f);  // log2(10000)/32
    float a = (float)l * inv;
    tab[i] = make_float2(sinf(a), cosf(a));
}

// ---------------------------------------------------------------------------
// bf16 GEMM  C[M,1024] = A[M,1024] @ W[1024,1024]^T (+bias)
// 128x128 tile, BK=32, 4 waves (2x2), global_load_lds w16, XOR-swizzled LDS.
// MODE 1: RoPE epilogue, bf16 out.  MODE 2: fp32 out.  MODE 3: vT bf16 out.
// ---------------------------------------------------------------------------
template <int MODE>
__global__ __launch_bounds__(256) void gemm_bt(const ushort_t* __restrict__ A,
                                               const ushort_t* __restrict__ Bw,
                                               const float* __restrict__ bias,
                                               void* __restrict__ outp,
                                               const float2* __restrict__ rope) {
    __shared__ __align__(16) ushort_t sA[128 * 32];
    __shared__ __align__(16) ushort_t sB[128 * 32];
    const int tid = threadIdx.x, lane = tid & 63, wv = tid >> 6;
    const int wr = wv >> 1, wc = wv & 1;
    const long bm = (long)blockIdx.x * 128;
    const int bn = blockIdx.y * 128;

    f32x4 acc[4][4] = {};

    // staging: per issue 256 thr x 16B = 64 rows x 64B; 2 issues per matrix
    const int srow = tid >> 2;       // 0..63
    const int sslot = tid & 3;       // 16B slot
    const int ca = sslot ^ (srow & 3);  // source chunk (swizzle, invariant to +64)
    const ushort_t* Ab = A + (bm + srow) * 1024 + ca * 8;
    const ushort_t* Bb = Bw + (long)(bn + srow) * 1024 + ca * 8;
    ushort_t* la = &sA[srow * 32 + sslot * 8];
    ushort_t* lb = &sB[srow * 32 + sslot * 8];

    for (int kt = 0; kt < 32; ++kt) {
        const int ko = kt * 32;
        gload_lds16(Ab + ko, la);
        gload_lds16(Ab + 64 * 1024 + ko, la + 64 * 32);
        gload_lds16(Bb + ko, lb);
        gload_lds16(Bb + 64 * 1024 + ko, lb + 64 * 32);
        __syncthreads();
        bf16x8 af[4], bfr[4];
#pragma unroll
        for (int mt = 0; mt < 4; ++mt) {
            int r = wr * 64 + mt * 16 + (lane & 15);
            int sl = (lane >> 4) ^ (r & 3);
            af[mt] = *(const bf16x8*)&sA[r * 32 + sl * 8];
        }
#pragma unroll
        for (int nt = 0; nt < 4; ++nt) {
            int r = wc * 64 + nt * 16 + (lane & 15);
            int sl = (lane >> 4) ^ (r & 3);
            bfr[nt] = *(const bf16x8*)&sB[r * 32 + sl * 8];
        }
#pragma unroll
        for (int mt = 0; mt < 4; ++mt)
#pragma unroll
            for (int nt = 0; nt < 4; ++nt)
                acc[mt][nt] = MFMA16(af[mt], bfr[nt], acc[mt][nt]);
        __syncthreads();
    }

    // epilogue: C[row=(lane>>4)*4+r][col=lane&15] per 16x16 tile
    if constexpr (MODE == 2) {
        float* out = (float*)outp;
#pragma unroll
        for (int nt = 0; nt < 4; ++nt) {
            int col = bn + wc * 64 + nt * 16 + (lane & 15);
            float bs = bias[col];
#pragma unroll
            for (int mt = 0; mt < 4; ++mt) {
                long g0 = bm + wr * 64 + mt * 16 + ((lane >> 4) << 2);
#pragma unroll
                for (int r = 0; r < 4; ++r)
                    out[(g0 + r) * 1024 + col] = acc[mt][nt][r] + bs;
            }
        }
    } else if constexpr (MODE == 1) {
        ushort_t* out = (ushort_t*)outp;
#pragma unroll
        for (int nt = 0; nt < 4; ++nt) {
            int col = bn + wc * 64 + nt * 16 + (lane & 15);
            float bs = bias[col];
            int c = (col & 63) >> 1;
            int outcol = (col & ~63) + ((col & 1) ? 32 : 0) + c;
#pragma unroll
            for (int mt = 0; mt < 4; ++mt) {
                int g0 = (int)bm + wr * 64 + mt * 16 + ((lane >> 4) << 2);
#pragma unroll
                for (int r = 0; r < 4; ++r) {
                    float y = acc[mt][nt][r] + bs;
                    float yp = __shfl_xor(y, 1);  // partner column (n^1)
                    int pos = (g0 + r) & 8191;
                    float2 sc = rope[pos * 32 + c];
                    // even col n=2c: xe=y,xo=yp -> out[c]    =  xe*sin + xo*cos
                    // odd  col     : xe=yp,xo=y -> out[32+c] = -xe*cos + xo*sin
                    float val = (col & 1) ? (y * sc.x - yp * sc.y)
                                          : (y * sc.x + yp * sc.y);
                    out[(long)(g0 + r) * 1024 + outcol] = f2bf(val);
                }
            }
        }
    } else {  // MODE 3: vT[b][h][d][w] <- y[m = b*512+w][n = h*64+d]
        ushort_t* out = (ushort_t*)outp;
#pragma unroll
        for (int nt = 0; nt < 4; ++nt) {
            int col = bn + wc * 64 + nt * 16 + (lane & 15);
            float bs = bias[col];
            int hh = col >> 6, d = col & 63;
#pragma unroll
            for (int mt = 0; mt < 4; ++mt) {
                int m0 = (int)bm + wr * 64 + mt * 16 + ((lane >> 4) << 2);
#pragma unroll
                for (int r = 0; r < 4; ++r) {
                    int m = m0 + r;
                    int bb = m >> 9, w = m & 511;
                    out[(((long)(bb * 16 + hh)) * 64 + d) * 512 + w] =
                        f2bf(acc[mt][nt][r] + bs);
                }
            }
        }
    }
}

// ---------------------------------------------------------------------------
// Attention: block = (b, h, group). 4 waves; wave owns 16 q rows x 512 keys.
// K staged in LDS (XOR-swizzled), V^T read from global (L2-resident, 2MB).
// Invalid cols (g*64+w >= L) -> score 0.0 pre-softmax (reference semantics).
// ---------------------------------------------------------------------------
__global__ __launch_bounds__(256) void attn(const ushort_t* __restrict__ qr,
                                            const ushort_t* __restrict__ kr,
                                            const ushort_t* __restrict__ vT,
                                            ushort_t* __restrict__ ctx) {
    __shared__ __align__(16) ushort_t sK[512 * 64];
    __shared__ __align__(16) ushort_t sP[4][16 * 72];  // stride 72 elems = 144B
    const int bid = blockIdx.x;
    const int g = bid & 127, h = (bid >> 7) & 15, b = bid >> 11;
    const int tid = threadIdx.x, lane = tid & 63, wv = tid >> 6;

    // stage K: 512 rows x 128B; swizzle: LDS slot s of row r holds chunk s^(r&7)
    {
        const int rr = tid >> 3, sl = tid & 7;
#pragma unroll
        for (int t = 0; t < 16; ++t) {
            int row = t * 32 + rr;
            int lk = g * 64 + row;
            lk = lk > 8191 ? 8191 : lk;  // clamp address (masked later)
            int chunk = sl ^ (row & 7);
            gload_lds16(kr + ((long)(b * 8192 + lk)) * 1024 + h * 64 + chunk * 8,
                        (char*)sK + t * 4096 + tid * 16);
        }
    }
    // Q fragments (direct from global; tile is tiny)
    const int qrow = g * 64 + wv * 16 + (lane & 15);
    const ushort_t* qp = qr + ((long)(b * 8192 + qrow)) * 1024 + h * 64 + ((lane >> 4) * 8);
    bf16x8 aq0 = *(const bf16x8*)qp;
    bf16x8 aq1 = *(const bf16x8*)(qp + 32);
    __syncthreads();

    // S = Q K^T : 32 N-tiles x 2 K-steps
    f32x4 s[32];
#pragma unroll
    for (int nt = 0; nt < 32; ++nt) s[nt] = (f32x4){0.f, 0.f, 0.f, 0.f};
#pragma unroll
    for (int nt = 0; nt < 32; ++nt) {
        int r = nt * 16 + (lane & 15);
        int x = r & 7;
        bf16x8 b0 = *(const bf16x8*)&sK[r * 64 + (((lane >> 4)) ^ x) * 8];
        bf16x8 b1 = *(const bf16x8*)&sK[r * 64 + ((4 + (lane >> 4)) ^ x) * 8];
        s[nt] = MFMA16(aq0, b0, s[nt]);
        s[nt] = MFMA16(aq1, b1, s[nt]);
    }

    // scale + mask (score -> 0.0 where g*64+col >= 8192)
    const int climit = 8192 - g * 64;
#pragma unroll
    for (int nt = 0; nt < 32; ++nt) {
        int c = nt * 16 + (lane & 15);
        bool inv = (c >= climit);
#pragma unroll
        for (int r = 0; r < 4; ++r) s[nt][r] = inv ? 0.0f : s[nt][r] * 0.125f;
    }

    // softmax: lane holds rows (lane>>4)*4+r, cols (lane&15)+16*nt
    float mx[4], si[4];
#pragma unroll
    for (int r = 0; r < 4; ++r) {
        float m = s[0][r];
#pragma unroll
        for (int nt = 1; nt < 32; ++nt) m = fmaxf(m, s[nt][r]);
#pragma unroll
        for (int d = 1; d < 16; d <<= 1) m = fmaxf(m, __shfl_xor(m, d));
        mx[r] = m;
    }
#pragma unroll
    for (int r = 0; r < 4; ++r) {
        float t = 0.f;
#pragma unroll
        for (int nt = 0; nt < 32; ++nt) {
            float e = __expf(s[nt][r] - mx[r]);
            s[nt][r] = e;
            t += e;
        }
#pragma unroll
        for (int d = 1; d < 16; d <<= 1) t += __shfl_xor(t, d);
        si[r] = 1.0f / t;
    }

    // ctx = P @ V : per 32-key chunk, re-lay P via wave-local LDS -> A frag
    f32x4 o[4];
#pragma unroll
    for (int d0 = 0; d0 < 4; ++d0) o[d0] = (f32x4){0.f, 0.f, 0.f, 0.f};
    ushort_t* pw = &sP[wv][0];
    const ushort_t* vb = vT + ((long)(b * 16 + h)) * 64 * 512;
#pragma unroll
    for (int kc = 0; kc < 16; ++kc) {
#pragma unroll
        for (int r = 0; r < 4; ++r) {
            int row = (lane >> 4) * 4 + r;
            pw[row * 72 + (lane & 15)] = f2bf(s[kc * 2][r] * si[r]);
            pw[row * 72 + 16 + (lane & 15)] = f2bf(s[kc * 2 + 1][r] * si[r]);
        }
        asm volatile("s_waitcnt lgkmcnt(0)" ::: "memory");
        bf16x8 pa = *(const bf16x8*)&pw[(lane & 15) * 72 + (lane >> 4) * 8];
#pragma unroll
        for (int d0 = 0; d0 < 4; ++d0) {
            bf16x8 bv = *(const bf16x8*)&vb[(long)(d0 * 16 + (lane & 15)) * 512 +
                                            kc * 32 + (lane >> 4) * 8];
            o[d0] = MFMA16(pa, bv, o[d0]);
        }
    }

    // write ctx (b, l, h*64+d) bf16
#pragma unroll
    for (int d0 = 0; d0 < 4; ++d0)
#pragma unroll
        for (int r = 0; r < 4; ++r) {
            int row = g * 64 + wv * 16 + (lane >> 4) * 4 + r;
            ctx[((long)(b * 8192 + row)) * 1024 + h * 64 + d0 * 16 + (lane & 15)] =
                f2bf(o[d0][r]);
        }
}

// ---------------------------------------------------------------------------
extern "C" void kernel_launch(void* const* d_in, const int* in_sizes, int n_in,
                              void* d_out, int out_size, void* d_ws, size_t ws_size,
                              hipStream_t stream) {
    const float* query = (const float*)d_in[0];
    const float* key_ = (const float*)d_in[1];
    const float* value = (const float*)d_in[2];
    const float* Wq = (const float*)d_in[3];
    const float* bq = (const float*)d_in[4];
    const float* Wk = (const float*)d_in[5];
    const float* bk = (const float*)d_in[6];
    const float* Wv = (const float*)d_in[7];
    const float* bv = (const float*)d_in[8];
    const float* Wo = (const float*)d_in[9];
    const float* bo = (const float*)d_in[10];
    float* out = (float*)d_out;
    char* ws = (char*)d_ws;

    // workspace layout (total ~110 MB); Xbf reused: query -> key -> ctx
    ushort_t* Xbf = (ushort_t*)(ws);
    ushort_t* Wqb = (ushort_t*)(ws + 33554432L);
    ushort_t* Wkb = (ushort_t*)(ws + 33554432L + 2097152L);
    ushort_t* Wvb = (ushort_t*)(ws + 33554432L + 2 * 2097152L);
    ushort_t* Wob = (ushort_t*)(ws + 33554432L + 3 * 2097152L);
    float2* rope = (float2*)(ws + 41943040L);
    ushort_t* qrb = (ushort_t*)(ws + 44040192L);
    ushort_t* krb = (ushort_t*)(ws + 77594624L);
    ushort_t* vin = (ushort_t*)(ws + 111149056L);
    ushort_t* vTb = (ushort_t*)(ws + 113246208L);

    rope_tab<<<1024, 256, 0, stream>>>(rope);
    cvt_bf16<<<512, 256, 0, stream>>>(Wq, Wqb, 131072);
    cvt_bf16<<<512, 256, 0, stream>>>(Wk, Wkb, 131072);
    cvt_bf16<<<512, 256, 0, stream>>>(Wv, Wvb, 131072);
    cvt_bf16<<<512, 256, 0, stream>>>(Wo, Wob, 131072);

    cvt_bf16<<<8192, 256, 0, stream>>>(query, Xbf, 2097152);
    gemm_bt<1><<<dim3(128, 8), 256, 0, stream>>>(Xbf, Wqb, bq, qrb, rope);
    cvt_bf16<<<8192, 256, 0, stream>>>(key_, Xbf, 2097152);
    gemm_bt<1><<<dim3(128, 8), 256, 0, stream>>>(Xbf, Wkb, bk, krb, rope);
    cvt_value<<<512, 256, 0, stream>>>(value, vin);
    gemm_bt<3><<<dim3(8, 8), 256, 0, stream>>>(vin, Wvb, bv, vTb, nullptr);

    attn<<<4096, 256, 0, stream>>>(qrb, krb, vTb, Xbf);
    gemm_bt<2><<<dim3(128, 8), 256, 0, stream>>>(Xbf, Wob, bo, out, nullptr);
}